// Round 20
// baseline (152.156 us; speedup 1.0000x reference)
//
#include <hip/hip_runtime.h>

#define L2E 1.4426950408889634f

typedef short bf16x8 __attribute__((ext_vector_type(8)));
typedef short short4v __attribute__((ext_vector_type(4)));
typedef float f32x4 __attribute__((ext_vector_type(4)));

__device__ __forceinline__ short bf16hi(float x) {
    return (short)(__builtin_bit_cast(unsigned int, x) >> 16);
}
__device__ __forceinline__ float bf16tof(short h) {
    return __builtin_bit_cast(float, ((unsigned int)(unsigned short)h) << 16);
}

// ---------------- Wsum ----------------
__global__ __launch_bounds__(256) void wsum_kernel(const float* __restrict__ W,
                                                   float* __restrict__ wsum) {
    int wave = threadIdx.x >> 6, lane = threadIdx.x & 63;
    int h = blockIdx.x * 4 + wave;
    const float* row = W + (size_t)h * 1024;
    float s = 0.f;
#pragma unroll
    for (int i = 0; i < 16; ++i) s += row[lane + 64 * i];
#pragma unroll
    for (int off = 32; off; off >>= 1) s += __shfl_xor(s, off, 64);
    if (lane == 0) wsum[h] = s;
}

// ------- prep: pair-major zero-diag transposed tables (R13, proven) ---------
__global__ __launch_bounds__(256) void prep_kernel(const float* __restrict__ cov,
                                                   const float* __restrict__ ld,
                                                   float2* __restrict__ covP,
                                                   float4* __restrict__ clP) {
    __shared__ float tc[32][33];
    __shared__ float tl[32][33];
    const int bx = blockIdx.x * 32, by = blockIdx.y * 32;
    const int x = threadIdx.x & 31;
    const int y = threadIdx.x >> 5;
#pragma unroll
    for (int i = 0; i < 32; i += 8) {
        int r = by + y + i, c = bx + x;
        float cv = cov[(size_t)r * 256 + c];
        float lv = ld[(size_t)r * 256 + c];
        if (r == c) { cv = 0.f; lv = 0.f; }
        tc[y + i][x] = cv; tl[y + i][x] = lv;
    }
    __syncthreads();
    const int k = by + x;
#pragma unroll
    for (int i2 = 0; i2 < 16; i2 += 8) {
        int y2 = y + i2;
        int jp = (bx >> 1) + y2;
        float c0 = tc[x][2 * y2],     l0 = tl[x][2 * y2];
        float c1 = tc[x][2 * y2 + 1], l1 = tl[x][2 * y2 + 1];
        covP[(size_t)jp * 256 + k] = make_float2(c0, c1);
        clP[(size_t)jp * 256 + k]  = make_float4(c0, l0, c1, l1);
    }
}

// ------- prep_w: W -> hi/lo bf16 fragment tables (R11 blocked map) ----------
// slot (lane l, elem i) <-> k = 32s + 16*(i>>2) + 4*(l>>4) + (i&3), n=16c+(l&15)
__global__ __launch_bounds__(256) void prep_w_kernel(const float* __restrict__ W,
                                                     short* __restrict__ WhT,
                                                     short* __restrict__ WlT) {
    int id = blockIdx.x * 256 + threadIdx.x;
    int rem = id & 1023;
    int s = id >> 10, c = rem >> 6, l = rem & 63;
    int n = 16 * c + (l & 15);
    int k0 = 32 * s + 4 * (l >> 4);
    const float* p = W + (size_t)n * 1024 + k0;
    short h[8], lo[8];
#pragma unroll
    for (int i = 0; i < 8; ++i) {
        float v = p[(i & 3) + 16 * (i >> 2)];
        short hh = bf16hi(v);
        h[i] = hh; lo[i] = bf16hi(v - bf16tof(hh));
    }
    *(bf16x8*)(WhT + (size_t)id * 8) = *(bf16x8*)h;
    *(bf16x8*)(WlT + (size_t)id * 8) = *(bf16x8*)lo;
}

// ------ values GEMM (MFMA hi/lo): C[2b][:] = x[b][0][:] @ W^T  (even rows) --
// values feeds out LINEARLY -> bf16-split error (~1e-4) is safe here.
__global__ __launch_bounds__(512) void vgemm_mfma(const float* __restrict__ X,
                                                  const short* __restrict__ WhT,
                                                  const short* __restrict__ WlT,
                                                  float* __restrict__ C) {
    __shared__ short Ah[2][64][8];
    __shared__ short Al[2][64][8];
    __shared__ short Wh[16][64][8];
    __shared__ short Wl[16][64][8];
    const int tid = threadIdx.x;
    const int l = tid & 63, w = tid >> 6;
    const int gm0 = blockIdx.x * 32;              // values-row tile (b index)

    const int xr = tid >> 3, xg = tid & 7;
    const float* Xp = X + (size_t)(2 * (gm0 + xr)) * 1024 + 4 * xg;  // row 2b

    float4 xv;
    bf16x8 wh0, wh1, wl0, wl1;
    if (tid < 256) xv = *(const float4*)(Xp);
    wh0 = *(const bf16x8*)(WhT + (size_t)tid * 8);
    wh1 = *(const bf16x8*)(WhT + (size_t)(tid + 512) * 8);
    wl0 = *(const bf16x8*)(WlT + (size_t)tid * 8);
    wl1 = *(const bf16x8*)(WlT + (size_t)(tid + 512) * 8);

    const int rt = w & 1, cg = w >> 1;
    f32x4 acc[4] = {};

    for (int s = 0; s < 32; ++s) {
        __syncthreads();
        if (tid < 256) {
            float vv[4] = {xv.x, xv.y, xv.z, xv.w};
            short h[4], lo[4];
#pragma unroll
            for (int i = 0; i < 4; ++i) {
                short hh = bf16hi(vv[i]);
                h[i] = hh; lo[i] = bf16hi(vv[i] - bf16tof(hh));
            }
            int lane = (xr & 15) + 16 * (xg & 3);
            int e0 = (xg >> 2) * 4;
            *(short4v*)&Ah[xr >> 4][lane][e0] = *(short4v*)h;
            *(short4v*)&Al[xr >> 4][lane][e0] = *(short4v*)lo;
        }
        ((bf16x8*)Wh)[tid]       = wh0;
        ((bf16x8*)Wh)[tid + 512] = wh1;
        ((bf16x8*)Wl)[tid]       = wl0;
        ((bf16x8*)Wl)[tid + 512] = wl1;
        __syncthreads();
        if (s < 31) {
            if (tid < 256) xv = *(const float4*)(Xp + (s + 1) * 32);
            const size_t wo = (size_t)(s + 1) * 8192;
            wh0 = *(const bf16x8*)(WhT + wo + (size_t)tid * 8);
            wh1 = *(const bf16x8*)(WhT + wo + (size_t)(tid + 512) * 8);
            wl0 = *(const bf16x8*)(WlT + wo + (size_t)tid * 8);
            wl1 = *(const bf16x8*)(WlT + wo + (size_t)(tid + 512) * 8);
        }
        bf16x8 ah = *(bf16x8*)&Ah[rt][l][0];
        bf16x8 al = *(bf16x8*)&Al[rt][l][0];
#pragma unroll
        for (int cc = 0; cc < 4; ++cc) {
            int c = cg * 4 + cc;
            bf16x8 bh = *(bf16x8*)&Wh[c][l][0];
            bf16x8 bl = *(bf16x8*)&Wl[c][l][0];
            acc[cc] = __builtin_amdgcn_mfma_f32_16x16x32_bf16(ah, bh, acc[cc], 0, 0, 0);
            acc[cc] = __builtin_amdgcn_mfma_f32_16x16x32_bf16(ah, bl, acc[cc], 0, 0, 0);
            acc[cc] = __builtin_amdgcn_mfma_f32_16x16x32_bf16(al, bh, acc[cc], 0, 0, 0);
        }
    }
    // D map (R11/R17-bit-verified layout): row=4*(l>>4)+reg, col=l&15
#pragma unroll
    for (int cc = 0; cc < 4; ++cc) {
        int c = cg * 4 + cc;
#pragma unroll
        for (int r = 0; r < 4; ++r) {
            int vrow = gm0 + rt * 16 + 4 * (l >> 4) + r;    // values index b
            C[(size_t)(2 * vrow) * 256 + c * 16 + (l & 15)] = acc[cc][r];
        }
    }
}

// ------ mask GEMM (fp32, R5 structure): C[2b+1][:] = x[b][1][:] @ W^T -------
// mask feeds the softmax normalizer (chaotic channel) -> must stay fp32.
#define BK 16
#define LDT 68

__global__ __launch_bounds__(256) void mgemm_fp32(const float* __restrict__ X,
                                                  const float* __restrict__ W,
                                                  float* __restrict__ C) {
    __shared__ float As[BK][LDT];
    __shared__ float Bs[BK][LDT];
    const int tid = threadIdx.x;
    const int row = tid >> 2;
    const int c4  = (tid & 3) << 2;
    const int gm0 = blockIdx.x * 64;              // mask-row tile (b index)
    const int gn0 = blockIdx.y * 64;
    const int tx = tid & 15, ty = tid >> 4;
    float acc[4][4] = {};
    const float* Xp = X + (size_t)(2 * (gm0 + row) + 1) * 1024 + c4;  // row 2b+1
    const float* Wp = W + (size_t)(gn0 + row) * 1024 + c4;

    float4 a = *(const float4*)(Xp);
    float4 b = *(const float4*)(Wp);
    for (int kt = 0; kt < 1024; kt += BK) {
        __syncthreads();
        As[c4 + 0][row] = a.x; As[c4 + 1][row] = a.y;
        As[c4 + 2][row] = a.z; As[c4 + 3][row] = a.w;
        Bs[c4 + 0][row] = b.x; Bs[c4 + 1][row] = b.y;
        Bs[c4 + 2][row] = b.z; Bs[c4 + 3][row] = b.w;
        __syncthreads();
        if (kt + BK < 1024) {
            a = *(const float4*)(Xp + kt + BK);
            b = *(const float4*)(Wp + kt + BK);
        }
#pragma unroll
        for (int kk = 0; kk < BK; ++kk) {
            float4 av = *(const float4*)&As[kk][ty << 2];
            float4 bv = *(const float4*)&Bs[kk][tx << 2];
            float am[4] = {av.x, av.y, av.z, av.w};
            float bn[4] = {bv.x, bv.y, bv.z, bv.w};
#pragma unroll
            for (int i = 0; i < 4; ++i)
#pragma unroll
                for (int j = 0; j < 4; ++j)
                    acc[i][j] = __builtin_fmaf(am[i], bn[j], acc[i][j]);
        }
    }
#pragma unroll
    for (int i = 0; i < 4; ++i) {
        float4 o = {acc[i][0], acc[i][1], acc[i][2], acc[i][3]};
        *(float4*)(C + (size_t)(2 * (gm0 + (ty << 2) + i) + 1) * 256 + gn0 + (tx << 2)) = o;
    }
}

// ---------------- Head (R13, proven) ----------------------------------------
#define NB 4

__global__ __launch_bounds__(256) void head_kernel(const float* __restrict__ C,
                                                   const float* __restrict__ wsum,
                                                   const float2* __restrict__ covP,
                                                   const float4* __restrict__ clP,
                                                   const float* __restrict__ cov,
                                                   const float* __restrict__ ld,
                                                   float* __restrict__ out) {
    __shared__ float4 omI[256];
    __shared__ float4 vaI[256];
    const int k = threadIdx.x;
    const int b0 = blockIdx.x * NB;

    const float ws = wsum[k];
    const float cdiag = cov[(size_t)k * 257];
    const float ldiag = ld[(size_t)k * 257];

    float mk[NB], vak[NB], omk[NB], sp[NB], pmax[NB], pmin[NB];
#pragma unroll
    for (int b = 0; b < NB; ++b) {
        float va = C[(size_t)(2 * (b0 + b)) * 256 + k];
        float ms = C[(size_t)(2 * (b0 + b) + 1) * 256 + k];
        float o  = ws - ms;
        mk[b] = ms; vak[b] = va; omk[b] = o;
        ((float*)&omI[k])[b] = o;
        ((float*)&vaI[k])[b] = va;
        sp[b] = 0.f; pmax[b] = 0.f; pmin[b] = 0.f;
    }
    __syncthreads();

    const float2* cp = covP + k;
#pragma unroll 4
    for (int jp = 0; jp < 128; ++jp) {
        float2 cv = cp[(size_t)jp * 256];
        float4 om0 = omI[2 * jp];
        float4 om1 = omI[2 * jp + 1];
        float o0[4] = {om0.x, om0.y, om0.z, om0.w};
        float o1[4] = {om1.x, om1.y, om1.z, om1.w};
#pragma unroll
        for (int b = 0; b < NB; ++b) {
            float p0 = cv.x * o0[b];
            float p1 = cv.y * o1[b];
            sp[b]  += p0 + p1;
            pmax[b] = fmaxf(fmaxf(pmax[b], p0), p1);
            pmin[b] = fminf(fminf(pmin[b], p0), p1);
        }
    }

    float c1[NB], c0[NB], ek[NB], se[NB], dp[NB];
#pragma unroll
    for (int b = 0; b < NB; ++b) {
        float m   = mk[b];
        float pkk = cdiag * omk[b];
        float rkk = __builtin_fmaf(m, pkk, 1.0f);
        float sum = __builtin_fmaf(m, sp[b] + pkk, 1.0f);
        float iv  = __builtin_amdgcn_rcpf(sum);
        float rmax = (m >= 0.f) ? m * pmax[b] : m * pmin[b];
        float rmin = (m >= 0.f) ? m * pmin[b] : m * pmax[b];
        rmax = fmaxf(rmax, rkk);
        rmin = fminf(rmin, rkk);
        float mx = (iv >= 0.f) ? iv * rmax : iv * rmin;   // == max_j w_j
        c1[b] = m * iv * L2E;
        c0[b] = -mx * L2E;
        ek[b] = __builtin_amdgcn_exp2f(__builtin_fmaf(rkk * iv, L2E, c0[b]));
        se[b] = 0.f; dp[b] = 0.f;
    }

    const float4* lp = clP + k;
#pragma unroll 4
    for (int jp = 0; jp < 128; ++jp) {
        float4 cl = lp[(size_t)jp * 256];
        float4 om0 = omI[2 * jp];
        float4 om1 = omI[2 * jp + 1];
        float4 va0 = vaI[2 * jp];
        float4 va1 = vaI[2 * jp + 1];
        float o0[4] = {om0.x, om0.y, om0.z, om0.w};
        float o1[4] = {om1.x, om1.y, om1.z, om1.w};
        float v0[4] = {va0.x, va0.y, va0.z, va0.w};
        float v1[4] = {va1.x, va1.y, va1.z, va1.w};
#pragma unroll
        for (int b = 0; b < NB; ++b) {
            float p0 = cl.x * o0[b];
            float e0 = __builtin_amdgcn_exp2f(__builtin_fmaf(p0, c1[b], c0[b]));
            float p1 = cl.z * o1[b];
            float e1 = __builtin_amdgcn_exp2f(__builtin_fmaf(p1, c1[b], c0[b]));
            se[b] += e0 + e1;
            dp[b]  = __builtin_fmaf(e0, cl.y * v0[b], dp[b]);
            dp[b]  = __builtin_fmaf(e1, cl.w * v1[b], dp[b]);
        }
    }

#pragma unroll
    for (int b = 0; b < NB; ++b) {
        float espur = __builtin_amdgcn_exp2f(c0[b]);
        float sef = se[b] + (ek[b] - espur);
        float dpf = __builtin_fmaf(ek[b], ldiag * vak[b], dp[b]);
        out[(size_t)(b0 + b) * 256 + k] = dpf * __builtin_amdgcn_rcpf(sef);
    }
}

extern "C" void kernel_launch(void* const* d_in, const int* in_sizes, int n_in,
                              void* d_out, int out_size, void* d_ws, size_t ws_size,
                              hipStream_t stream) {
    const float* x    = (const float*)d_in[0];   // [4096,2,1024]
    const float* W    = (const float*)d_in[1];   // [256,1024]
    const float* cov  = (const float*)d_in[2];   // [256,256]
    const float* ldng = (const float*)d_in[3];   // [256,256]
    float* out = (float*)d_out;                  // [4096,256]

    // d_ws: R13-proven footprint
    float*  C    = (float*)d_ws;                         // [8192,256]
    float*  wsum = C + (size_t)8192 * 256;               // [256]
    float2* covP = (float2*)(wsum + 256);                // [128*256] pairs
    float4* clP  = (float4*)((float*)covP + 65536);      // [128*256] quads

    // W hi/lo tables in d_out scratch (R16-proven placement); head overwrites.
    short* WhT = (short*)d_out;                          // [32768*8]
    short* WlT = WhT + (size_t)262144;                   // [32768*8]

    wsum_kernel<<<64, 256, 0, stream>>>(W, wsum);
    prep_kernel<<<dim3(8, 8), 256, 0, stream>>>(cov, ldng, covP, clP);
    prep_w_kernel<<<128, 256, 0, stream>>>(W, WhT, WlT);
    vgemm_mfma<<<128, 512, 0, stream>>>(x, WhT, WlT, C);     // even rows (values)
    mgemm_fp32<<<dim3(64, 4), 256, 0, stream>>>(x, W, C);    // odd rows (mask)
    head_kernel<<<1024, 256, 0, stream>>>(C, wsum, covP, clP, cov, ldng, out);
}

// Round 21
// 148.496 us; speedup vs baseline: 1.0246x; 1.0246x over previous
//
#include <hip/hip_runtime.h>

#define L2E 1.4426950408889634f

typedef short bf16x8 __attribute__((ext_vector_type(8)));
typedef short short4v __attribute__((ext_vector_type(4)));
typedef float f32x4 __attribute__((ext_vector_type(4)));

__device__ __forceinline__ short bf16hi(float x) {
    return (short)(__builtin_bit_cast(unsigned int, x) >> 16);
}
__device__ __forceinline__ float bf16tof(short h) {
    return __builtin_bit_cast(float, ((unsigned int)(unsigned short)h) << 16);
}

// ---------------- Wsum ----------------
__global__ __launch_bounds__(256) void wsum_kernel(const float* __restrict__ W,
                                                   float* __restrict__ wsum) {
    int wave = threadIdx.x >> 6, lane = threadIdx.x & 63;
    int h = blockIdx.x * 4 + wave;
    const float* row = W + (size_t)h * 1024;
    float s = 0.f;
#pragma unroll
    for (int i = 0; i < 16; ++i) s += row[lane + 64 * i];
#pragma unroll
    for (int off = 32; off; off >>= 1) s += __shfl_xor(s, off, 64);
    if (lane == 0) wsum[h] = s;
}

// ------- prep: pair-major zero-diag transposed tables (R13, proven) ---------
__global__ __launch_bounds__(256) void prep_kernel(const float* __restrict__ cov,
                                                   const float* __restrict__ ld,
                                                   float2* __restrict__ covP,
                                                   float4* __restrict__ clP) {
    __shared__ float tc[32][33];
    __shared__ float tl[32][33];
    const int bx = blockIdx.x * 32, by = blockIdx.y * 32;
    const int x = threadIdx.x & 31;
    const int y = threadIdx.x >> 5;
#pragma unroll
    for (int i = 0; i < 32; i += 8) {
        int r = by + y + i, c = bx + x;
        float cv = cov[(size_t)r * 256 + c];
        float lv = ld[(size_t)r * 256 + c];
        if (r == c) { cv = 0.f; lv = 0.f; }
        tc[y + i][x] = cv; tl[y + i][x] = lv;
    }
    __syncthreads();
    const int k = by + x;
#pragma unroll
    for (int i2 = 0; i2 < 16; i2 += 8) {
        int y2 = y + i2;
        int jp = (bx >> 1) + y2;
        float c0 = tc[x][2 * y2],     l0 = tl[x][2 * y2];
        float c1 = tc[x][2 * y2 + 1], l1 = tl[x][2 * y2 + 1];
        covP[(size_t)jp * 256 + k] = make_float2(c0, c1);
        clP[(size_t)jp * 256 + k]  = make_float4(c0, l0, c1, l1);
    }
}

// ------- prep_w: W -> hi/lo bf16 fragment tables (R11 blocked map, proven) --
// slot (lane l, elem i) <-> k = 32s + 16*(i>>2) + 4*(l>>4) + (i&3), n=16c+(l&15)
__global__ __launch_bounds__(256) void prep_w_kernel(const float* __restrict__ W,
                                                     short* __restrict__ WhT,
                                                     short* __restrict__ WlT) {
    int id = blockIdx.x * 256 + threadIdx.x;
    int rem = id & 1023;
    int s = id >> 10, c = rem >> 6, l = rem & 63;
    int n = 16 * c + (l & 15);
    int k0 = 32 * s + 4 * (l >> 4);
    const float* p = W + (size_t)n * 1024 + k0;
    short h[8], lo[8];
#pragma unroll
    for (int i = 0; i < 8; ++i) {
        float v = p[(i & 3) + 16 * (i >> 2)];
        short hh = bf16hi(v);
        h[i] = hh; lo[i] = bf16hi(v - bf16tof(hh));
    }
    *(bf16x8*)(WhT + (size_t)id * 8) = *(bf16x8*)h;
    *(bf16x8*)(WlT + (size_t)id * 8) = *(bf16x8*)lo;
}

// ------ values GEMM (MFMA hi/lo): C[2b][:] = x[b][0][:] @ W^T  (even rows) --
// R20-proven numerics; now BN=128 / grid 256 -> 1 block per CU.
__global__ __launch_bounds__(512) void vgemm_mfma(const float* __restrict__ X,
                                                  const short* __restrict__ WhT,
                                                  const short* __restrict__ WlT,
                                                  float* __restrict__ C) {
    __shared__ short Ah[2][64][8];
    __shared__ short Al[2][64][8];
    __shared__ short Wh[8][64][8];     // 8 ctiles (this block's N half)
    __shared__ short Wl[8][64][8];
    const int tid = threadIdx.x;
    const int l = tid & 63, w = tid >> 6;
    const int gm0 = (blockIdx.x >> 1) * 32;       // values-row tile (b index)
    const int nh  = blockIdx.x & 1;               // N half: ctiles [8nh, 8nh+8)
    const size_t wbase = (size_t)(nh * 8) * 64;   // entry offset of ctile slice

    const int xr = tid >> 3, xg = tid & 7;
    const float* Xp = X + (size_t)(2 * (gm0 + xr)) * 1024 + 4 * xg;  // row 2b

    float4 xv;
    bf16x8 wh0, wl0;
    if (tid < 256) xv = *(const float4*)(Xp);
    wh0 = *(const bf16x8*)(WhT + (wbase + tid) * 8);
    wl0 = *(const bf16x8*)(WlT + (wbase + tid) * 8);

    const int rt = w & 1, cg = w >> 1;            // cg in [0,4): 2 ctiles each
    f32x4 acc[2] = {};

    for (int s = 0; s < 32; ++s) {
        __syncthreads();
        if (tid < 256) {
            float vv[4] = {xv.x, xv.y, xv.z, xv.w};
            short h[4], lo[4];
#pragma unroll
            for (int i = 0; i < 4; ++i) {
                short hh = bf16hi(vv[i]);
                h[i] = hh; lo[i] = bf16hi(vv[i] - bf16tof(hh));
            }
            int lane = (xr & 15) + 16 * (xg & 3);
            int e0 = (xg >> 2) * 4;
            *(short4v*)&Ah[xr >> 4][lane][e0] = *(short4v*)h;
            *(short4v*)&Al[xr >> 4][lane][e0] = *(short4v*)lo;
        }
        ((bf16x8*)Wh)[tid] = wh0;                 // 512 entries == 512 threads
        ((bf16x8*)Wl)[tid] = wl0;
        __syncthreads();
        if (s < 31) {
            if (tid < 256) xv = *(const float4*)(Xp + (s + 1) * 32);
            const size_t wo = (size_t)(s + 1) * 1024 + wbase + tid;
            wh0 = *(const bf16x8*)(WhT + wo * 8);
            wl0 = *(const bf16x8*)(WlT + wo * 8);
        }
        bf16x8 ah = *(bf16x8*)&Ah[rt][l][0];
        bf16x8 al = *(bf16x8*)&Al[rt][l][0];
#pragma unroll
        for (int cc = 0; cc < 2; ++cc) {
            int c = cg * 2 + cc;
            bf16x8 bh = *(bf16x8*)&Wh[c][l][0];
            bf16x8 bl = *(bf16x8*)&Wl[c][l][0];
            acc[cc] = __builtin_amdgcn_mfma_f32_16x16x32_bf16(ah, bh, acc[cc], 0, 0, 0);
            acc[cc] = __builtin_amdgcn_mfma_f32_16x16x32_bf16(ah, bl, acc[cc], 0, 0, 0);
            acc[cc] = __builtin_amdgcn_mfma_f32_16x16x32_bf16(al, bh, acc[cc], 0, 0, 0);
        }
    }
    // D map (R20-verified): row=4*(l>>4)+reg, col=l&15
#pragma unroll
    for (int cc = 0; cc < 2; ++cc) {
        int col = nh * 128 + (cg * 2 + cc) * 16 + (l & 15);
#pragma unroll
        for (int r = 0; r < 4; ++r) {
            int vrow = gm0 + rt * 16 + 4 * (l >> 4) + r;    // values index b
            C[(size_t)(2 * vrow) * 256 + col] = acc[cc][r];
        }
    }
}

// ------ mask GEMM (fp32, R5 structure): C[2b+1][:] = x[b][1][:] @ W^T -------
// mask feeds the softmax normalizer (chaotic channel) -> must stay fp32.
#define BK 16
#define LDT 68

__global__ __launch_bounds__(256) void mgemm_fp32(const float* __restrict__ X,
                                                  const float* __restrict__ W,
                                                  float* __restrict__ C) {
    __shared__ float As[BK][LDT];
    __shared__ float Bs[BK][LDT];
    const int tid = threadIdx.x;
    const int row = tid >> 2;
    const int c4  = (tid & 3) << 2;
    const int gm0 = blockIdx.x * 64;              // mask-row tile (b index)
    const int gn0 = blockIdx.y * 64;
    const int tx = tid & 15, ty = tid >> 4;
    float acc[4][4] = {};
    const float* Xp = X + (size_t)(2 * (gm0 + row) + 1) * 1024 + c4;  // row 2b+1
    const float* Wp = W + (size_t)(gn0 + row) * 1024 + c4;

    float4 a = *(const float4*)(Xp);
    float4 b = *(const float4*)(Wp);
    for (int kt = 0; kt < 1024; kt += BK) {
        __syncthreads();
        As[c4 + 0][row] = a.x; As[c4 + 1][row] = a.y;
        As[c4 + 2][row] = a.z; As[c4 + 3][row] = a.w;
        Bs[c4 + 0][row] = b.x; Bs[c4 + 1][row] = b.y;
        Bs[c4 + 2][row] = b.z; Bs[c4 + 3][row] = b.w;
        __syncthreads();
        if (kt + BK < 1024) {
            a = *(const float4*)(Xp + kt + BK);
            b = *(const float4*)(Wp + kt + BK);
        }
#pragma unroll
        for (int kk = 0; kk < BK; ++kk) {
            float4 av = *(const float4*)&As[kk][ty << 2];
            float4 bv = *(const float4*)&Bs[kk][tx << 2];
            float am[4] = {av.x, av.y, av.z, av.w};
            float bn[4] = {bv.x, bv.y, bv.z, bv.w};
#pragma unroll
            for (int i = 0; i < 4; ++i)
#pragma unroll
                for (int j = 0; j < 4; ++j)
                    acc[i][j] = __builtin_fmaf(am[i], bn[j], acc[i][j]);
        }
    }
#pragma unroll
    for (int i = 0; i < 4; ++i) {
        float4 o = {acc[i][0], acc[i][1], acc[i][2], acc[i][3]};
        *(float4*)(C + (size_t)(2 * (gm0 + (ty << 2) + i) + 1) * 256 + gn0 + (tx << 2)) = o;
    }
}

// ---------------- Head (R13, proven) ----------------------------------------
#define NB 4

__global__ __launch_bounds__(256) void head_kernel(const float* __restrict__ C,
                                                   const float* __restrict__ wsum,
                                                   const float2* __restrict__ covP,
                                                   const float4* __restrict__ clP,
                                                   const float* __restrict__ cov,
                                                   const float* __restrict__ ld,
                                                   float* __restrict__ out) {
    __shared__ float4 omI[256];
    __shared__ float4 vaI[256];
    const int k = threadIdx.x;
    const int b0 = blockIdx.x * NB;

    const float ws = wsum[k];
    const float cdiag = cov[(size_t)k * 257];
    const float ldiag = ld[(size_t)k * 257];

    float mk[NB], vak[NB], omk[NB], sp[NB], pmax[NB], pmin[NB];
#pragma unroll
    for (int b = 0; b < NB; ++b) {
        float va = C[(size_t)(2 * (b0 + b)) * 256 + k];
        float ms = C[(size_t)(2 * (b0 + b) + 1) * 256 + k];
        float o  = ws - ms;
        mk[b] = ms; vak[b] = va; omk[b] = o;
        ((float*)&omI[k])[b] = o;
        ((float*)&vaI[k])[b] = va;
        sp[b] = 0.f; pmax[b] = 0.f; pmin[b] = 0.f;
    }
    __syncthreads();

    const float2* cp = covP + k;
#pragma unroll 4
    for (int jp = 0; jp < 128; ++jp) {
        float2 cv = cp[(size_t)jp * 256];
        float4 om0 = omI[2 * jp];
        float4 om1 = omI[2 * jp + 1];
        float o0[4] = {om0.x, om0.y, om0.z, om0.w};
        float o1[4] = {om1.x, om1.y, om1.z, om1.w};
#pragma unroll
        for (int b = 0; b < NB; ++b) {
            float p0 = cv.x * o0[b];
            float p1 = cv.y * o1[b];
            sp[b]  += p0 + p1;
            pmax[b] = fmaxf(fmaxf(pmax[b], p0), p1);
            pmin[b] = fminf(fminf(pmin[b], p0), p1);
        }
    }

    float c1[NB], c0[NB], ek[NB], se[NB], dp[NB];
#pragma unroll
    for (int b = 0; b < NB; ++b) {
        float m   = mk[b];
        float pkk = cdiag * omk[b];
        float rkk = __builtin_fmaf(m, pkk, 1.0f);
        float sum = __builtin_fmaf(m, sp[b] + pkk, 1.0f);
        float iv  = __builtin_amdgcn_rcpf(sum);
        float rmax = (m >= 0.f) ? m * pmax[b] : m * pmin[b];
        float rmin = (m >= 0.f) ? m * pmin[b] : m * pmax[b];
        rmax = fmaxf(rmax, rkk);
        rmin = fminf(rmin, rkk);
        float mx = (iv >= 0.f) ? iv * rmax : iv * rmin;   // == max_j w_j
        c1[b] = m * iv * L2E;
        c0[b] = -mx * L2E;
        ek[b] = __builtin_amdgcn_exp2f(__builtin_fmaf(rkk * iv, L2E, c0[b]));
        se[b] = 0.f; dp[b] = 0.f;
    }

    const float4* lp = clP + k;
#pragma unroll 4
    for (int jp = 0; jp < 128; ++jp) {
        float4 cl = lp[(size_t)jp * 256];
        float4 om0 = omI[2 * jp];
        float4 om1 = omI[2 * jp + 1];
        float4 va0 = vaI[2 * jp];
        float4 va1 = vaI[2 * jp + 1];
        float o0[4] = {om0.x, om0.y, om0.z, om0.w};
        float o1[4] = {om1.x, om1.y, om1.z, om1.w};
        float v0[4] = {va0.x, va0.y, va0.z, va0.w};
        float v1[4] = {va1.x, va1.y, va1.z, va1.w};
#pragma unroll
        for (int b = 0; b < NB; ++b) {
            float p0 = cl.x * o0[b];
            float e0 = __builtin_amdgcn_exp2f(__builtin_fmaf(p0, c1[b], c0[b]));
            float p1 = cl.z * o1[b];
            float e1 = __builtin_amdgcn_exp2f(__builtin_fmaf(p1, c1[b], c0[b]));
            se[b] += e0 + e1;
            dp[b]  = __builtin_fmaf(e0, cl.y * v0[b], dp[b]);
            dp[b]  = __builtin_fmaf(e1, cl.w * v1[b], dp[b]);
        }
    }

#pragma unroll
    for (int b = 0; b < NB; ++b) {
        float espur = __builtin_amdgcn_exp2f(c0[b]);
        float sef = se[b] + (ek[b] - espur);
        float dpf = __builtin_fmaf(ek[b], ldiag * vak[b], dp[b]);
        out[(size_t)(b0 + b) * 256 + k] = dpf * __builtin_amdgcn_rcpf(sef);
    }
}

extern "C" void kernel_launch(void* const* d_in, const int* in_sizes, int n_in,
                              void* d_out, int out_size, void* d_ws, size_t ws_size,
                              hipStream_t stream) {
    const float* x    = (const float*)d_in[0];   // [4096,2,1024]
    const float* W    = (const float*)d_in[1];   // [256,1024]
    const float* cov  = (const float*)d_in[2];   // [256,256]
    const float* ldng = (const float*)d_in[3];   // [256,256]
    float* out = (float*)d_out;                  // [4096,256]

    // d_ws: R13-proven footprint
    float*  C    = (float*)d_ws;                         // [8192,256]
    float*  wsum = C + (size_t)8192 * 256;               // [256]
    float2* covP = (float2*)(wsum + 256);                // [128*256] pairs
    float4* clP  = (float4*)((float*)covP + 65536);      // [128*256] quads

    // W hi/lo tables in d_out scratch (R16/R20-proven placement).
    short* WhT = (short*)d_out;                          // [32768*8]
    short* WlT = WhT + (size_t)262144;                   // [32768*8]

    wsum_kernel<<<64, 256, 0, stream>>>(W, wsum);
    prep_kernel<<<dim3(8, 8), 256, 0, stream>>>(cov, ldng, covP, clP);
    prep_w_kernel<<<128, 256, 0, stream>>>(W, WhT, WlT);
    vgemm_mfma<<<256, 512, 0, stream>>>(x, WhT, WlT, C);     // even rows (values)
    mgemm_fp32<<<dim3(64, 4), 256, 0, stream>>>(x, W, C);    // odd rows (mask)
    head_kernel<<<1024, 256, 0, stream>>>(C, wsum, covP, clP, cov, ldng, out);
}